// Round 3
// baseline (151174.512 us; speedup 1.0000x reference)
//
#include <hip/hip_runtime.h>
#include <hip/hip_bf16.h>

// STN_RNN: B=32, T=4096, IN=1, H=512, gates=2048, k=0.5 blend.
// 256 WGs = 32 batches x 8 weight slices; per-step h exchange through global
// double buffer + per-batch monotonic counter (agent-scope release/acquire).
// Dtype-adaptive: detect kernel classifies inputs as bf16 vs fp32 at runtime.

#define NBATCH 32
#define NT     4096
#define NH     512
#define WPB    8
#define UNITS  64

// ws byte offsets
#define FLAG_OFF  0u
#define CTR_OFF   64u        // 32 counters, stride 16 u32 (64B) = 2048 B
#define BIAS_OFF  4096u      // 2048 f32
#define WIH_OFF   12288u     // 2048 f32
#define XF_OFF    20480u     // 131072 f32 = 512 KiB
#define HBUF_OFF  544768u    // 2*32*512 f32 = 128 KiB
#define WT_OFF    675840u    // 512x2048, bf16 (2 MiB) or f32 (4 MiB)

__device__ __forceinline__ float bf2f(unsigned short u) {
    union { unsigned int i; float f; } v; v.i = ((unsigned int)u) << 16; return v.f;
}
__device__ __forceinline__ unsigned short f2bf_rne(float f) {
    union { unsigned int i; float f; } v; v.f = f;
    return (unsigned short)((v.i + 0x7fffu + ((v.i >> 16) & 1u)) >> 16);
}
__device__ __forceinline__ float sigm(float x) {
    return 1.0f / (1.0f + __expf(-x));
}
__device__ __forceinline__ float tanh_fast(float x) {
    float e = __expf(-2.0f * fabsf(x));
    float r = (1.0f - e) / (1.0f + e);
    return copysignf(r, x);
}
// col = wg*256 + (gate*64 + u)  ->  row = gate*512 + wg*64 + u
__device__ __forceinline__ int col2row(int col) {
    int wg = col >> 8, r = col & 255, g = (r >> 6) & 3, u = r & 63;
    return g * 512 + wg * 64 + u;
}

// ---- 1 block: classify dtype of inputs, zero counters ----
// W_ih has 2048 elems, |w| < 0.0443. If storage is bf16, EVERY even-index u16
// decodes in-bound. If fp32, even u16s are float low-halves -> random exponent
// -> only ~48% decode in-bound.
__global__ void prep_detect(const unsigned short* __restrict__ wih_u,
                            int* __restrict__ flagp,
                            unsigned int* __restrict__ ctr) {
    __shared__ int cnt;
    if (threadIdx.x == 0) cnt = 0;
    __syncthreads();
    int local = 0;
    for (int i = threadIdx.x; i < 1024; i += 256) {
        float v = bf2f(wih_u[2 * i]);
        if (fabsf(v) <= 0.0625f) local++;
    }
    atomicAdd(&cnt, local);
    __syncthreads();
    if (threadIdx.x == 0) *flagp = (cnt >= 1000) ? 1 : 0;
    if (threadIdx.x < 32) ctr[threadIdx.x * 16] = 0u;
}

// ---- canonicalize W_hh (permuted-transposed), bias, W_ih, x ----
__global__ void prep_conv(const void* __restrict__ x,
                          const void* __restrict__ Wih,
                          const void* __restrict__ Whh,
                          const void* __restrict__ bih,
                          const void* __restrict__ bhh,
                          const int* __restrict__ flagp,
                          void* __restrict__ WT,
                          float* __restrict__ bias_p,
                          float* __restrict__ wih_p,
                          float* __restrict__ Xf) {
    int idx = blockIdx.x * blockDim.x + threadIdx.x;   // 4096*256 = 1048576
    int isbf = *flagp;
    int k = idx >> 11, col = idx & 2047;
    int row = col2row(col);
    size_t si = (size_t)row * 512 + k;
    if (isbf) {
        ((unsigned short*)WT)[(size_t)k * 2048 + col] = ((const unsigned short*)Whh)[si];
    } else {
        ((float*)WT)[(size_t)k * 2048 + col] = ((const float*)Whh)[si];
    }
    if (idx < 2048) {
        float bi, bh, wi;
        if (isbf) {
            bi = bf2f(((const unsigned short*)bih)[row]);
            bh = bf2f(((const unsigned short*)bhh)[row]);
            wi = bf2f(((const unsigned short*)Wih)[row]);
        } else {
            bi = ((const float*)bih)[row];
            bh = ((const float*)bhh)[row];
            wi = ((const float*)Wih)[row];
        }
        bias_p[col] = bi + bh;
        wih_p[col]  = wi;
    }
    if (idx < NBATCH * NT) {
        Xf[idx] = isbf ? bf2f(((const unsigned short*)x)[idx])
                       : ((const float*)x)[idx];
    }
}

__global__ void __launch_bounds__(256) rnn_kernel(
    const float* __restrict__ Xf,
    const void* __restrict__ WT,
    const float* __restrict__ bias_p,
    const float* __restrict__ wih_p,
    float* __restrict__ hbuf,
    unsigned int* __restrict__ ctr,
    const int* __restrict__ flagp,
    void* __restrict__ out)
{
    const int tid = threadIdx.x;
    const int bid = blockIdx.x;
    const int b   = bid & 31;
    const int wg  = bid >> 5;
    const int isbf = *flagp;

    __shared__ float hsh[512];
    __shared__ float parts[4][256];
    __shared__ float gates[256];
    __shared__ float cst[UNITS];
    __shared__ float hst[UNITS];

    if (tid < UNITS) { cst[tid] = 0.0f; hst[tid] = 0.0f; }

    const int jq = tid & 63;
    const int ks = tid >> 6;
    const unsigned short* wb_u = (const unsigned short*)WT
        + (size_t)(ks * 128) * 2048 + (wg * 256 + jq * 4);
    const float* wb_f = (const float*)WT
        + (size_t)(ks * 128) * 2048 + (wg * 256 + jq * 4);

    const float biasr = bias_p[wg * 256 + tid];
    const float wihr  = wih_p[wg * 256 + tid];

    unsigned int* ctrb = ctr + b * 16;   // one cacheline per batch
    unsigned short* outb_u = (unsigned short*)out + (size_t)b * NT * NH;
    float*          outb_f = (float*)out + (size_t)b * NT * NH;

    unsigned int broken = 0;

    for (int t = 0; t < NT; ++t) {
        // ---- acquire h_t ----
        if (t == 0) {
            hsh[tid] = 0.0f; hsh[tid + 256] = 0.0f;
        } else {
            if (tid == 0 && !broken) {
                unsigned int target = 8u * (unsigned int)t;
                int g = 0;
                while (__hip_atomic_load(ctrb, __ATOMIC_ACQUIRE,
                                         __HIP_MEMORY_SCOPE_AGENT) < target) {
                    __builtin_amdgcn_s_sleep(2);
                    if (++g > 8000000) { broken = 1; break; }
                }
            }
            __syncthreads();
            __builtin_amdgcn_fence(__ATOMIC_ACQUIRE, "agent");
            const float* hin = hbuf + (((t & 1) * NBATCH + b) << 9);
            ((float2*)hsh)[tid] = ((const float2*)hin)[tid];
        }
        __syncthreads();

        // ---- gate dots: 4 cols x 128 k per thread ----
        float a0 = 0.f, a1 = 0.f, a2 = 0.f, a3 = 0.f;
        const float* hq = hsh + ks * 128;
        if (isbf) {
            const unsigned short* p = wb_u;
            #pragma unroll 8
            for (int it = 0; it < 128; ++it) {
                float hk = hq[it];
                ushort4 w = *(const ushort4*)p;
                p += 2048;
                a0 = fmaf(hk, bf2f(w.x), a0);
                a1 = fmaf(hk, bf2f(w.y), a1);
                a2 = fmaf(hk, bf2f(w.z), a2);
                a3 = fmaf(hk, bf2f(w.w), a3);
            }
        } else {
            const float* p = wb_f;
            #pragma unroll 8
            for (int it = 0; it < 128; ++it) {
                float hk = hq[it];
                float4 w = *(const float4*)p;
                p += 2048;
                a0 = fmaf(hk, w.x, a0);
                a1 = fmaf(hk, w.y, a1);
                a2 = fmaf(hk, w.z, a2);
                a3 = fmaf(hk, w.w, a3);
            }
        }
        *(float4*)&parts[ks][jq * 4] = make_float4(a0, a1, a2, a3);
        __syncthreads();

        // ---- reduce k-quarters + bias + x term ----
        float xt = Xf[b * NT + t];
        gates[tid] = parts[0][tid] + parts[1][tid] + parts[2][tid] + parts[3][tid]
                   + biasr + xt * wihr;
        __syncthreads();

        // ---- LSTM cell + STN blend ----
        if (tid < UNITS) {
            float ig = sigm(gates[tid]);
            float fg = sigm(gates[64 + tid]);
            float gg = tanh_fast(gates[128 + tid]);
            float og = sigm(gates[192 + tid]);
            float cold = cst[tid], hold = hst[tid];
            float cnew = fg * cold + ig * gg;
            float hnew = og * tanh_fast(cnew);
            float cb = 0.5f * (cold + cnew);
            float hb = 0.5f * (hold + hnew);
            cst[tid] = cb; hst[tid] = hb;
            float* hout = hbuf + ((((t + 1) & 1) * NBATCH + b) << 9);
            hout[wg * 64 + tid] = hb;
            if (isbf) outb_u[(size_t)t * NH + wg * 64 + tid] = f2bf_rne(hb);
            else      outb_f[(size_t)t * NH + wg * 64 + tid] = hb;
        }
        __builtin_amdgcn_fence(__ATOMIC_RELEASE, "agent");
        __syncthreads();
        if (tid == 0)
            __hip_atomic_fetch_add(ctrb, 1u, __ATOMIC_RELEASE,
                                   __HIP_MEMORY_SCOPE_AGENT);
    }

    // ---- final_state [h | c] ----
    if (tid < UNITS) {
        size_t fsbase = (size_t)NBATCH * NT * NH + (size_t)b * (2 * NH);
        if (isbf) {
            ((unsigned short*)out)[fsbase + wg * 64 + tid]       = f2bf_rne(hst[tid]);
            ((unsigned short*)out)[fsbase + 512 + wg * 64 + tid] = f2bf_rne(cst[tid]);
        } else {
            ((float*)out)[fsbase + wg * 64 + tid]       = hst[tid];
            ((float*)out)[fsbase + 512 + wg * 64 + tid] = cst[tid];
        }
    }
}

extern "C" void kernel_launch(void* const* d_in, const int* in_sizes, int n_in,
                              void* d_out, int out_size, void* d_ws, size_t ws_size,
                              hipStream_t stream) {
    const void* x   = d_in[0];
    const void* Wih = d_in[1];
    const void* Whh = d_in[2];
    const void* bih = d_in[3];
    const void* bhh = d_in[4];

    char* ws = (char*)d_ws;
    int* flagp          = (int*)(ws + FLAG_OFF);
    unsigned int* ctrp  = (unsigned int*)(ws + CTR_OFF);
    float* bias_p       = (float*)(ws + BIAS_OFF);
    float* wih_p        = (float*)(ws + WIH_OFF);
    float* Xf           = (float*)(ws + XF_OFF);
    float* hbuf         = (float*)(ws + HBUF_OFF);
    void* WT            = (void*)(ws + WT_OFF);

    prep_detect<<<1, 256, 0, stream>>>((const unsigned short*)Wih, flagp, ctrp);
    prep_conv<<<4096, 256, 0, stream>>>(x, Wih, Whh, bih, bhh, flagp,
                                        WT, bias_p, wih_p, Xf);
    rnn_kernel<<<256, 256, 0, stream>>>(Xf, WT, bias_p, wih_p, hbuf, ctrp,
                                        flagp, d_out);
}

// Round 4
// 31169.061 us; speedup vs baseline: 4.8501x; 4.8501x over previous
//
#include <hip/hip_runtime.h>
#include <hip/hip_bf16.h>

// STN_RNN: B=32, T=4096, IN=1, H=512, gates=2048, k=0.5 blend.
// 256 WGs = 32 batches x 8 weight slices; per-step h exchange through global
// double buffer + per-batch monotonic counter.
// R4: ALL cross-WG traffic via RELAXED agent-scope atomics (sc0/sc1 cache-
// bypass, coherent at L3) -- no buffer_inv/buffer_wbl2 cache-wide fences.
// Producer ordering via per-wave s_waitcnt vmcnt(0) (h-stores and counter
// post both live in wave 0). Weights stay L2-resident across all steps.

#define NBATCH 32
#define NT     4096
#define NH     512
#define WPB    8
#define UNITS  64

// ws byte offsets
#define FLAG_OFF  0u
#define CTR_OFF   64u        // 32 counters, stride 16 u32 (64B)
#define BIAS_OFF  4096u      // 2048 f32
#define WIH_OFF   12288u     // 2048 f32
#define XF_OFF    20480u     // 131072 f32 = 512 KiB
#define HBUF_OFF  544768u    // 2*32*512 f32 = 128 KiB
#define WT_OFF    675840u    // 512x2048, bf16 (2 MiB) or f32 (4 MiB)

__device__ __forceinline__ float bf2f(unsigned short u) {
    union { unsigned int i; float f; } v; v.i = ((unsigned int)u) << 16; return v.f;
}
__device__ __forceinline__ unsigned short f2bf_rne(float f) {
    union { unsigned int i; float f; } v; v.f = f;
    return (unsigned short)((v.i + 0x7fffu + ((v.i >> 16) & 1u)) >> 16);
}
__device__ __forceinline__ float sigm(float x) {
    return 1.0f / (1.0f + __expf(-x));
}
__device__ __forceinline__ float tanh_fast(float x) {
    float e = __expf(-2.0f * fabsf(x));
    float r = (1.0f - e) / (1.0f + e);
    return copysignf(r, x);
}
// col = wg*256 + (gate*64 + u)  ->  row = gate*512 + wg*64 + u
__device__ __forceinline__ int col2row(int col) {
    int wg = col >> 8, r = col & 255, g = (r >> 6) & 3, u = r & 63;
    return g * 512 + wg * 64 + u;
}

// ---- dtype detect (bf16 vs f32) + zero counters ----
__global__ void prep_detect(const unsigned short* __restrict__ wih_u,
                            int* __restrict__ flagp,
                            unsigned int* __restrict__ ctr) {
    __shared__ int cnt;
    if (threadIdx.x == 0) cnt = 0;
    __syncthreads();
    int local = 0;
    for (int i = threadIdx.x; i < 1024; i += 256) {
        float v = bf2f(wih_u[2 * i]);
        if (fabsf(v) <= 0.0625f) local++;
    }
    atomicAdd(&cnt, local);
    __syncthreads();
    if (threadIdx.x == 0) *flagp = (cnt >= 1000) ? 1 : 0;
    if (threadIdx.x < 32) ctr[threadIdx.x * 16] = 0u;
}

// ---- canonicalize W_hh (permuted-transposed), bias, W_ih, x ----
__global__ void prep_conv(const void* __restrict__ x,
                          const void* __restrict__ Wih,
                          const void* __restrict__ Whh,
                          const void* __restrict__ bih,
                          const void* __restrict__ bhh,
                          const int* __restrict__ flagp,
                          void* __restrict__ WT,
                          float* __restrict__ bias_p,
                          float* __restrict__ wih_p,
                          float* __restrict__ Xf) {
    int idx = blockIdx.x * blockDim.x + threadIdx.x;   // 1048576
    int isbf = *flagp;
    int k = idx >> 11, col = idx & 2047;
    int row = col2row(col);
    size_t si = (size_t)row * 512 + k;
    if (isbf) {
        ((unsigned short*)WT)[(size_t)k * 2048 + col] = ((const unsigned short*)Whh)[si];
    } else {
        ((float*)WT)[(size_t)k * 2048 + col] = ((const float*)Whh)[si];
    }
    if (idx < 2048) {
        float bi, bh, wi;
        if (isbf) {
            bi = bf2f(((const unsigned short*)bih)[row]);
            bh = bf2f(((const unsigned short*)bhh)[row]);
            wi = bf2f(((const unsigned short*)Wih)[row]);
        } else {
            bi = ((const float*)bih)[row];
            bh = ((const float*)bhh)[row];
            wi = ((const float*)Wih)[row];
        }
        bias_p[col] = bi + bh;
        wih_p[col]  = wi;
    }
    if (idx < NBATCH * NT) {
        Xf[idx] = isbf ? bf2f(((const unsigned short*)x)[idx])
                       : ((const float*)x)[idx];
    }
}

__global__ void __launch_bounds__(256) rnn_kernel(
    const float* __restrict__ Xf,
    const void* __restrict__ WT,
    const float* __restrict__ bias_p,
    const float* __restrict__ wih_p,
    float* __restrict__ hbuf,
    unsigned int* __restrict__ ctr,
    const int* __restrict__ flagp,
    void* __restrict__ out)
{
    const int tid = threadIdx.x;
    const int bid = blockIdx.x;
    const int b   = bid & 31;
    const int wg  = bid >> 5;
    const int isbf = *flagp;

    __shared__ float hsh[512];
    __shared__ float parts[4][256];
    __shared__ float gates[256];
    __shared__ float cst[UNITS];
    __shared__ float hst[UNITS];

    if (tid < UNITS) { cst[tid] = 0.0f; hst[tid] = 0.0f; }

    const int jq = tid & 63;
    const int ks = tid >> 6;
    const unsigned short* wb_u = (const unsigned short*)WT
        + (size_t)(ks * 128) * 2048 + (wg * 256 + jq * 4);
    const float* wb_f = (const float*)WT
        + (size_t)(ks * 128) * 2048 + (wg * 256 + jq * 4);

    const float biasr = bias_p[wg * 256 + tid];
    const float wihr  = wih_p[wg * 256 + tid];

    unsigned int* ctrb = ctr + b * 16;   // one cacheline per batch
    unsigned short* outb_u = (unsigned short*)out + (size_t)b * NT * NH;
    float*          outb_f = (float*)out + (size_t)b * NT * NH;

    unsigned int broken = 0;

    for (int t = 0; t < NT; ++t) {
        // ---- acquire h_t ----
        if (t == 0) {
            hsh[tid] = 0.0f; hsh[tid + 256] = 0.0f;
        } else {
            if (tid == 0 && !broken) {
                unsigned int target = 8u * (unsigned int)t;
                int g = 0;
                while (__hip_atomic_load(ctrb, __ATOMIC_RELAXED,
                                         __HIP_MEMORY_SCOPE_AGENT) < target) {
                    __builtin_amdgcn_s_sleep(1);
                    if (++g > 16000000) { broken = 1; break; }
                }
            }
            __syncthreads();
            __atomic_signal_fence(__ATOMIC_SEQ_CST);
            // coherent (cache-bypass) 8B loads: 2 floats/thread
            const unsigned long long* hin = (const unsigned long long*)
                (hbuf + (((t & 1) * NBATCH + b) << 9));
            unsigned long long hv = __hip_atomic_load(hin + tid, __ATOMIC_RELAXED,
                                                      __HIP_MEMORY_SCOPE_AGENT);
            union { unsigned long long u; float f[2]; } cvt; cvt.u = hv;
            hsh[2 * tid]     = cvt.f[0];
            hsh[2 * tid + 1] = cvt.f[1];
        }
        __syncthreads();

        // ---- gate dots: 4 cols x 128 k per thread ----
        float a0 = 0.f, a1 = 0.f, a2 = 0.f, a3 = 0.f;
        const float* hq = hsh + ks * 128;
        if (isbf) {
            const unsigned short* p = wb_u;
            #pragma unroll 8
            for (int it = 0; it < 128; ++it) {
                float hk = hq[it];
                ushort4 w = *(const ushort4*)p;
                p += 2048;
                a0 = fmaf(hk, bf2f(w.x), a0);
                a1 = fmaf(hk, bf2f(w.y), a1);
                a2 = fmaf(hk, bf2f(w.z), a2);
                a3 = fmaf(hk, bf2f(w.w), a3);
            }
        } else {
            const float* p = wb_f;
            #pragma unroll 8
            for (int it = 0; it < 128; ++it) {
                float hk = hq[it];
                float4 w = *(const float4*)p;
                p += 2048;
                a0 = fmaf(hk, w.x, a0);
                a1 = fmaf(hk, w.y, a1);
                a2 = fmaf(hk, w.z, a2);
                a3 = fmaf(hk, w.w, a3);
            }
        }
        *(float4*)&parts[ks][jq * 4] = make_float4(a0, a1, a2, a3);
        __syncthreads();

        // ---- reduce k-quarters + bias + x term ----
        float xt = Xf[b * NT + t];
        gates[tid] = parts[0][tid] + parts[1][tid] + parts[2][tid] + parts[3][tid]
                   + biasr + xt * wihr;
        __syncthreads();

        // ---- LSTM cell + STN blend (wave 0 only: tid<64) ----
        if (tid < UNITS) {
            float ig = sigm(gates[tid]);
            float fg = sigm(gates[64 + tid]);
            float gg = tanh_fast(gates[128 + tid]);
            float og = sigm(gates[192 + tid]);
            float cold = cst[tid], hold = hst[tid];
            float cnew = fg * cold + ig * gg;
            float hnew = og * tanh_fast(cnew);
            float cb = 0.5f * (cold + cnew);
            float hb = 0.5f * (hold + hnew);
            cst[tid] = cb; hst[tid] = hb;
            // coherent (cache-bypass) h publish
            float* hout = hbuf + ((((t + 1) & 1) * NBATCH + b) << 9);
            __hip_atomic_store(&hout[wg * 64 + tid], hb, __ATOMIC_RELAXED,
                               __HIP_MEMORY_SCOPE_AGENT);
            if (isbf) outb_u[(size_t)t * NH + wg * 64 + tid] = f2bf_rne(hb);
            else      outb_f[(size_t)t * NH + wg * 64 + tid] = hb;
        }
        // wave 0: drain h-stores, then post. (s_waitcnt is per-wave; the
        // h-stores and this post are both in wave 0.)
        __atomic_signal_fence(__ATOMIC_SEQ_CST);
        if (tid < 64) {
            __builtin_amdgcn_s_waitcnt(0);
            if (tid == 0)
                __hip_atomic_fetch_add(ctrb, 1u, __ATOMIC_RELAXED,
                                       __HIP_MEMORY_SCOPE_AGENT);
        }
        __syncthreads();   // guards hsh/parts/gates reuse next iter
    }

    // ---- final_state [h | c] ----
    if (tid < UNITS) {
        size_t fsbase = (size_t)NBATCH * NT * NH + (size_t)b * (2 * NH);
        if (isbf) {
            ((unsigned short*)out)[fsbase + wg * 64 + tid]       = f2bf_rne(hst[tid]);
            ((unsigned short*)out)[fsbase + 512 + wg * 64 + tid] = f2bf_rne(cst[tid]);
        } else {
            ((float*)out)[fsbase + wg * 64 + tid]       = hst[tid];
            ((float*)out)[fsbase + 512 + wg * 64 + tid] = cst[tid];
        }
    }
}

extern "C" void kernel_launch(void* const* d_in, const int* in_sizes, int n_in,
                              void* d_out, int out_size, void* d_ws, size_t ws_size,
                              hipStream_t stream) {
    const void* x   = d_in[0];
    const void* Wih = d_in[1];
    const void* Whh = d_in[2];
    const void* bih = d_in[3];
    const void* bhh = d_in[4];

    char* ws = (char*)d_ws;
    int* flagp          = (int*)(ws + FLAG_OFF);
    unsigned int* ctrp  = (unsigned int*)(ws + CTR_OFF);
    float* bias_p       = (float*)(ws + BIAS_OFF);
    float* wih_p        = (float*)(ws + WIH_OFF);
    float* Xf           = (float*)(ws + XF_OFF);
    float* hbuf         = (float*)(ws + HBUF_OFF);
    void* WT            = (void*)(ws + WT_OFF);

    prep_detect<<<1, 256, 0, stream>>>((const unsigned short*)Wih, flagp, ctrp);
    prep_conv<<<4096, 256, 0, stream>>>(x, Wih, Whh, bih, bhh, flagp,
                                        WT, bias_p, wih_p, Xf);
    rnn_kernel<<<256, 256, 0, stream>>>(Xf, WT, bias_p, wih_p, hbuf, ctrp,
                                        flagp, d_out);
}